// Round 1
// baseline (1809.021 us; speedup 1.0000x reference)
//
#include <hip/hip_runtime.h>
#include <math.h>

// Problem constants: B=8, N1=64, N2=4096, C=768, H=12, hd=64, scale=1/8.
// Stages:
//   Qb  [512,768]   = x @ Wq^T                      (sgemm64_nt)
//   KVb [32768,1536]= y @ W_kv^T  (K cols 0..767, V cols 768..1535) (sgemm128_nt)
//   pass1/combine: per (b,h,row j) softmax stats (max, 1/sum) over n2=4096
//   pass2: E[b,n2,h*64+j] = softmax_p * V  -> written into d_out
//   proj_inplace: d_out = E @ Wproj^T + b   (block caches its 16 rows in LDS first)

// ---------------- 64x64 tile SGEMM, C[M,N] = A[M,K] @ B[N,K]^T ----------------
__global__ __launch_bounds__(256) void sgemm64_nt(
    const float* __restrict__ A, int lda,
    const float* __restrict__ B, int ldb,
    float* __restrict__ C, int ldc, int K)
{
  __shared__ float As[16][68];
  __shared__ float Bs[16][68];
  const int tid = threadIdx.x;
  const int tx = tid & 15, ty = tid >> 4;
  const int m0 = blockIdx.y * 64, n0 = blockIdx.x * 64;
  const int f = tid & 3, r = tid >> 2;   // loader: f = k-float4, r = row 0..63
  float acc[4][4];
#pragma unroll
  for (int i = 0; i < 4; ++i)
#pragma unroll
    for (int j = 0; j < 4; ++j) acc[i][j] = 0.f;

  for (int k0 = 0; k0 < K; k0 += 16) {
    float4 a = *(const float4*)(A + (size_t)(m0 + r) * lda + k0 + f * 4);
    float4 b = *(const float4*)(B + (size_t)(n0 + r) * ldb + k0 + f * 4);
    As[f*4+0][r] = a.x; As[f*4+1][r] = a.y; As[f*4+2][r] = a.z; As[f*4+3][r] = a.w;
    Bs[f*4+0][r] = b.x; Bs[f*4+1][r] = b.y; Bs[f*4+2][r] = b.z; Bs[f*4+3][r] = b.w;
    __syncthreads();
#pragma unroll
    for (int k = 0; k < 16; ++k) {
      float4 xa = *(const float4*)(&As[k][ty * 4]);
      float4 xb = *(const float4*)(&Bs[k][tx * 4]);
      float av[4] = {xa.x, xa.y, xa.z, xa.w};
      float bv[4] = {xb.x, xb.y, xb.z, xb.w};
#pragma unroll
      for (int i = 0; i < 4; ++i)
#pragma unroll
        for (int j = 0; j < 4; ++j) acc[i][j] = fmaf(av[i], bv[j], acc[i][j]);
    }
    __syncthreads();
  }
#pragma unroll
  for (int i = 0; i < 4; ++i) {
    float4 o = make_float4(acc[i][0], acc[i][1], acc[i][2], acc[i][3]);
    *(float4*)(C + (size_t)(m0 + ty * 4 + i) * ldc + n0 + tx * 4) = o;
  }
}

// ------------- 128x128 tile SGEMM (reg-double-buffered), optional bias -------------
__global__ __launch_bounds__(256) void sgemm128_nt(
    const float* __restrict__ A, int lda,
    const float* __restrict__ B, int ldb,
    float* __restrict__ C, int ldc, int K,
    const float* __restrict__ bias)
{
  __shared__ float As[16][132];
  __shared__ float Bs[16][132];
  const int tid = threadIdx.x;
  const int tx = tid & 15, ty = tid >> 4;
  const int m0 = blockIdx.y * 128, n0 = blockIdx.x * 128;
  const int f = tid & 3, r = tid >> 2;   // loader: 64 rows, handles r and r+64
  const float* Ap = A + (size_t)(m0 + r) * lda + f * 4;
  const float* Bp = B + (size_t)(n0 + r) * ldb + f * 4;

  float acc[8][8];
#pragma unroll
  for (int i = 0; i < 8; ++i)
#pragma unroll
    for (int j = 0; j < 8; ++j) acc[i][j] = 0.f;

  float4 a0 = *(const float4*)(Ap);
  float4 a1 = *(const float4*)(Ap + (size_t)64 * lda);
  float4 b0 = *(const float4*)(Bp);
  float4 b1 = *(const float4*)(Bp + (size_t)64 * ldb);

  for (int k0 = 16;; k0 += 16) {
    As[f*4+0][r] = a0.x; As[f*4+1][r] = a0.y; As[f*4+2][r] = a0.z; As[f*4+3][r] = a0.w;
    As[f*4+0][r+64] = a1.x; As[f*4+1][r+64] = a1.y; As[f*4+2][r+64] = a1.z; As[f*4+3][r+64] = a1.w;
    Bs[f*4+0][r] = b0.x; Bs[f*4+1][r] = b0.y; Bs[f*4+2][r] = b0.z; Bs[f*4+3][r] = b0.w;
    Bs[f*4+0][r+64] = b1.x; Bs[f*4+1][r+64] = b1.y; Bs[f*4+2][r+64] = b1.z; Bs[f*4+3][r+64] = b1.w;
    __syncthreads();
    const bool more = k0 < K;
    if (more) {
      a0 = *(const float4*)(Ap + k0);
      a1 = *(const float4*)(Ap + k0 + (size_t)64 * lda);
      b0 = *(const float4*)(Bp + k0);
      b1 = *(const float4*)(Bp + k0 + (size_t)64 * ldb);
    }
#pragma unroll
    for (int k = 0; k < 16; ++k) {
      float4 xa0 = *(const float4*)(&As[k][ty * 4]);
      float4 xa1 = *(const float4*)(&As[k][ty * 4 + 64]);
      float4 xb0 = *(const float4*)(&Bs[k][tx * 4]);
      float4 xb1 = *(const float4*)(&Bs[k][tx * 4 + 64]);
      float av[8] = {xa0.x, xa0.y, xa0.z, xa0.w, xa1.x, xa1.y, xa1.z, xa1.w};
      float bv[8] = {xb0.x, xb0.y, xb0.z, xb0.w, xb1.x, xb1.y, xb1.z, xb1.w};
#pragma unroll
      for (int i = 0; i < 8; ++i)
#pragma unroll
        for (int j = 0; j < 8; ++j) acc[i][j] = fmaf(av[i], bv[j], acc[i][j]);
    }
    __syncthreads();
    if (!more) break;
  }

  float bb0[4] = {0.f, 0.f, 0.f, 0.f}, bb1[4] = {0.f, 0.f, 0.f, 0.f};
  if (bias) {
#pragma unroll
    for (int j = 0; j < 4; ++j) {
      bb0[j] = bias[n0 + tx * 4 + j];
      bb1[j] = bias[n0 + 64 + tx * 4 + j];
    }
  }
#pragma unroll
  for (int i = 0; i < 8; ++i) {
    const int row = m0 + ty * 4 + (i & 3) + (i >> 2) * 64;
    float* crow = C + (size_t)row * ldc + n0;
    float4 o0 = make_float4(acc[i][0] + bb0[0], acc[i][1] + bb0[1],
                            acc[i][2] + bb0[2], acc[i][3] + bb0[3]);
    float4 o1 = make_float4(acc[i][4] + bb1[0], acc[i][5] + bb1[1],
                            acc[i][6] + bb1[2], acc[i][7] + bb1[3]);
    *(float4*)(crow + tx * 4) = o0;
    *(float4*)(crow + 64 + tx * 4) = o1;
  }
}

// ---------------- attention pass 1: partial (max, sumexp) per (b,h,j,chunk) ----------------
// grid (32, 12, 8), 256 threads; chunk = 128 keys; thread (j=tid/4, sub=tid&3) covers 32 keys.
__global__ __launch_bounds__(256) void attn_pass1(
    const float* __restrict__ Q,      // [512,768]
    const float* __restrict__ KV,     // [32768,1536], K cols 0..767
    float* __restrict__ parts)        // [96][32][64][2]
{
  const int chunk = blockIdx.x, h = blockIdx.y, b = blockIdx.z;
  const int tid = threadIdx.x;
  __shared__ float Ks[128][68];
  __shared__ float rmx[64][4];
  __shared__ float rsm[64][4];
  {
    const int f = tid & 15, r0 = tid >> 4;
    const float* base = KV + (size_t)(b * 4096 + chunk * 128 + r0) * 1536 + h * 64 + f * 4;
#pragma unroll
    for (int rr = 0; rr < 8; ++rr) {
      float4 v = *(const float4*)(base + (size_t)rr * 16 * 1536);
      *(float4*)(&Ks[r0 + rr * 16][f * 4]) = v;
    }
  }
  const int j = tid >> 2, sub = tid & 3;
  float4 q[16];
  {
    const float* qrow = Q + (size_t)(b * 64 + j) * 768 + h * 64;
#pragma unroll
    for (int c = 0; c < 16; ++c) q[c] = *(const float4*)(qrow + c * 4);
  }
  __syncthreads();

  float mx = -1e30f, sm = 0.f;
  for (int i = 0; i < 32; ++i) {
    const int n = sub + i * 4;
    float s = 0.f;
#pragma unroll
    for (int c = 0; c < 16; ++c) {
      float4 k4 = *(const float4*)(&Ks[n][c * 4]);
      s = fmaf(q[c].x, k4.x, s); s = fmaf(q[c].y, k4.y, s);
      s = fmaf(q[c].z, k4.z, s); s = fmaf(q[c].w, k4.w, s);
    }
    s *= 0.125f;
    if (s > mx) { sm = sm * __expf(mx - s) + 1.f; mx = s; }
    else        { sm += __expf(s - mx); }
  }
  rmx[j][sub] = mx; rsm[j][sub] = sm;
  __syncthreads();
  if (tid < 64) {
    float m0 = rmx[tid][0], m1 = rmx[tid][1], m2 = rmx[tid][2], m3 = rmx[tid][3];
    float g = fmaxf(fmaxf(m0, m1), fmaxf(m2, m3));
    float ssum = rsm[tid][0] * __expf(m0 - g) + rsm[tid][1] * __expf(m1 - g)
               + rsm[tid][2] * __expf(m2 - g) + rsm[tid][3] * __expf(m3 - g);
    const int bh = b * 12 + h;
    float* p = parts + ((size_t)(bh * 32 + chunk) * 64 + tid) * 2;
    p[0] = g; p[1] = ssum;
  }
}

// ---------------- combine partials -> (gmax, 1/gsum) ----------------
__global__ void attn_combine(const float* __restrict__ parts, float* __restrict__ stats)
{
  const int bh = blockIdx.x, j = threadIdx.x;   // 96 blocks x 64 threads
  float pm[32], ps[32];
  float g = -1e30f;
#pragma unroll
  for (int c = 0; c < 32; ++c) {
    const float* p = parts + ((size_t)(bh * 32 + c) * 64 + j) * 2;
    pm[c] = p[0]; ps[c] = p[1];
    g = fmaxf(g, pm[c]);
  }
  float s = 0.f;
#pragma unroll
  for (int c = 0; c < 32; ++c) s += ps[c] * __expf(pm[c] - g);
  stats[(size_t)(bh * 64 + j) * 2]     = g;
  stats[(size_t)(bh * 64 + j) * 2 + 1] = 1.f / s;
}

// ---------------- pass 2: E[b,n2,h*64+j] = p * V ----------------
__global__ __launch_bounds__(256) void attn_pass2(
    const float* __restrict__ Q, const float* __restrict__ KV,
    const float* __restrict__ stats, float* __restrict__ E)
{
  const int chunk = blockIdx.x, h = blockIdx.y, b = blockIdx.z;
  const int tid = threadIdx.x;
  __shared__ float Ks[128][68];
  {
    const int f = tid & 15, r0 = tid >> 4;
    const float* base = KV + (size_t)(b * 4096 + chunk * 128 + r0) * 1536 + h * 64 + f * 4;
#pragma unroll
    for (int rr = 0; rr < 8; ++rr) {
      float4 v = *(const float4*)(base + (size_t)rr * 16 * 1536);
      *(float4*)(&Ks[r0 + rr * 16][f * 4]) = v;
    }
  }
  const int j = tid >> 2, sub = tid & 3;
  float4 q[16];
  {
    const float* qrow = Q + (size_t)(b * 64 + j) * 768 + h * 64;
#pragma unroll
    for (int c = 0; c < 16; ++c) q[c] = *(const float4*)(qrow + c * 4);
  }
  const int bh = b * 12 + h;
  const float gmax = stats[(size_t)(bh * 64 + j) * 2];
  const float ginv = stats[(size_t)(bh * 64 + j) * 2 + 1];
  __syncthreads();

  for (int i = 0; i < 32; ++i) {
    const int n = sub + i * 4;
    const int n2 = chunk * 128 + n;
    float s = 0.f;
#pragma unroll
    for (int c = 0; c < 16; ++c) {
      float4 k4 = *(const float4*)(&Ks[n][c * 4]);
      s = fmaf(q[c].x, k4.x, s); s = fmaf(q[c].y, k4.y, s);
      s = fmaf(q[c].z, k4.z, s); s = fmaf(q[c].w, k4.w, s);
    }
    s *= 0.125f;
    const float p = __expf(s - gmax) * ginv;
    const float v = KV[(size_t)(b * 4096 + n2) * 1536 + 768 + h * 64 + j];
    E[(size_t)(b * 4096 + n2) * 768 + h * 64 + j] = p * v;
  }
}

// ---------------- final projection, IN-PLACE on d_out ----------------
// Each block owns 16 rows exclusively: loads them to LDS fully, then overwrites.
__global__ __launch_bounds__(256) void proj_inplace(
    float* __restrict__ EO,            // [32768,768] in/out
    const float* __restrict__ W,       // [768,768]
    const float* __restrict__ bias)    // [768]
{
  const int m0 = blockIdx.x * 16;
  const int tid = threadIdx.x;
  __shared__ float Es[16][776];
  __shared__ float Ws[16][260];
#pragma unroll
  for (int it = 0; it < 12; ++it) {
    int idx = tid + it * 256;           // 0..3071 float4s
    int rr = idx / 192, ff = idx % 192;
    *(float4*)(&Es[rr][ff * 4]) = *(const float4*)(EO + (size_t)(m0 + rr) * 768 + ff * 4);
  }
  const int mg = tid >> 6;   // 0..3 -> rows mg*4..mg*4+3 (wave-uniform)
  const int ng = tid & 63;   // cols ng*4 in 256-wide tile
  const int fw = tid & 3, rw = tid >> 2;

  for (int nt = 0; nt < 3; ++nt) {
    float acc[4][4];
#pragma unroll
    for (int i = 0; i < 4; ++i)
#pragma unroll
      for (int jj = 0; jj < 4; ++jj) acc[i][jj] = 0.f;

    float4 wreg[4];
#pragma unroll
    for (int rr = 0; rr < 4; ++rr)
      wreg[rr] = *(const float4*)(W + (size_t)(nt * 256 + rw + rr * 64) * 768 + fw * 4);

    int kb = 0;
    for (int k0 = 16;; k0 += 16) {
      __syncthreads();   // Ws free to overwrite (also covers initial Es barrier)
#pragma unroll
      for (int rr = 0; rr < 4; ++rr) {
        const int n = rw + rr * 64;
        Ws[fw*4+0][n] = wreg[rr].x; Ws[fw*4+1][n] = wreg[rr].y;
        Ws[fw*4+2][n] = wreg[rr].z; Ws[fw*4+3][n] = wreg[rr].w;
      }
      __syncthreads();
      const bool more = k0 < 768;
      if (more) {
#pragma unroll
        for (int rr = 0; rr < 4; ++rr)
          wreg[rr] = *(const float4*)(W + (size_t)(nt * 256 + rw + rr * 64) * 768 + k0 + fw * 4);
      }
#pragma unroll
      for (int k = 0; k < 16; ++k) {
        const float e0 = Es[mg * 4 + 0][kb + k];
        const float e1 = Es[mg * 4 + 1][kb + k];
        const float e2 = Es[mg * 4 + 2][kb + k];
        const float e3 = Es[mg * 4 + 3][kb + k];
        float4 w4 = *(const float4*)(&Ws[k][ng * 4]);
        acc[0][0] = fmaf(e0, w4.x, acc[0][0]); acc[0][1] = fmaf(e0, w4.y, acc[0][1]);
        acc[0][2] = fmaf(e0, w4.z, acc[0][2]); acc[0][3] = fmaf(e0, w4.w, acc[0][3]);
        acc[1][0] = fmaf(e1, w4.x, acc[1][0]); acc[1][1] = fmaf(e1, w4.y, acc[1][1]);
        acc[1][2] = fmaf(e1, w4.z, acc[1][2]); acc[1][3] = fmaf(e1, w4.w, acc[1][3]);
        acc[2][0] = fmaf(e2, w4.x, acc[2][0]); acc[2][1] = fmaf(e2, w4.y, acc[2][1]);
        acc[2][2] = fmaf(e2, w4.z, acc[2][2]); acc[2][3] = fmaf(e2, w4.w, acc[2][3]);
        acc[3][0] = fmaf(e3, w4.x, acc[3][0]); acc[3][1] = fmaf(e3, w4.y, acc[3][1]);
        acc[3][2] = fmaf(e3, w4.z, acc[3][2]); acc[3][3] = fmaf(e3, w4.w, acc[3][3]);
      }
      kb = k0;
      if (!more) break;
    }
    const float4 bb = *(const float4*)(bias + nt * 256 + ng * 4);
#pragma unroll
    for (int i = 0; i < 4; ++i) {
      float4 o = make_float4(acc[i][0] + bb.x, acc[i][1] + bb.y,
                             acc[i][2] + bb.z, acc[i][3] + bb.w);
      *(float4*)(EO + (size_t)(m0 + mg * 4 + i) * 768 + nt * 256 + ng * 4) = o;
    }
  }
}

extern "C" void kernel_launch(void* const* d_in, const int* in_sizes, int n_in,
                              void* d_out, int out_size, void* d_ws, size_t ws_size,
                              hipStream_t stream) {
  const float* x     = (const float*)d_in[0];   // [8,64,768]
  const float* y     = (const float*)d_in[1];   // [8,4096,768]
  const float* Wqkv  = (const float*)d_in[2];   // [2304,768]
  const float* Wproj = (const float*)d_in[3];   // [768,768]
  const float* bproj = (const float*)d_in[4];   // [768]
  float* out = (float*)d_out;                   // [8,4096,768]
  float* ws  = (float*)d_ws;

  // workspace layout (floats): Q 393216 | KV 50331648 | parts 393216 | stats 12288
  float* Qb    = ws;
  float* KVb   = Qb + 393216;
  float* parts = KVb + (size_t)50331648;
  float* stats = parts + 393216;

  // Q projection: [512,768] = x @ Wq^T
  sgemm64_nt<<<dim3(12, 8), 256, 0, stream>>>(x, 768, Wqkv, 768, Qb, 768, 768);
  // KV projection: [32768,1536] = y @ W_kv^T (W rows 768..2303)
  sgemm128_nt<<<dim3(12, 256), 256, 0, stream>>>(
      y, 768, Wqkv + (size_t)768 * 768, 768, KVb, 1536, 768, nullptr);
  // softmax stats (two-pass flash style)
  attn_pass1<<<dim3(32, 12, 8), 256, 0, stream>>>(Qb, KVb, parts);
  attn_combine<<<96, 64, 0, stream>>>(parts, stats);
  // E = p * v into d_out
  attn_pass2<<<dim3(32, 12, 8), 256, 0, stream>>>(Qb, KVb, stats, out);
  // d_out = E @ Wproj^T + b, in-place
  proj_inplace<<<2048, 256, 0, stream>>>(out, Wproj, bproj);
}

// Round 2
// 524.015 us; speedup vs baseline: 3.4522x; 3.4522x over previous
//
#include <hip/hip_runtime.h>
#include <math.h>

// B=8, N1=64, N2=4096, C=768, H=12, hd=64, scale=1/8.
// Pipeline:
//   cast y, W_kv, W_proj to bf16
//   Qb  [512,768] f32   = x @ Wq^T            (fp32 sgemm64 — small, keeps softmax inputs accurate)
//   KVb [32768,1536] bf16 = ybf @ Wkv^T       (bf16 MFMA gemm, bf16 output)
//   pass1/combine: per (b,h,row) softmax stats over n2=4096 (fp32 math)
//   pass2: Ebf[b,n2,h*64+j] = p * v  (bf16)
//   out [32768,768] f32 = Ebf @ Wproj^T + b   (bf16 MFMA gemm, f32 output)

typedef __attribute__((ext_vector_type(8))) short short8;
typedef __attribute__((ext_vector_type(4))) float f32x4;

__device__ __forceinline__ ushort f2bf(float x) {
  unsigned u = __float_as_uint(x);
  u += 0x7fffu + ((u >> 16) & 1u);          // round-to-nearest-even
  return (ushort)(u >> 16);
}
__device__ __forceinline__ float bf2f(ushort h) {
  return __uint_as_float((unsigned)h << 16);
}

// ---------------- fp32 -> bf16 cast, 8 elems/thread ----------------
__global__ __launch_bounds__(256) void cast_f32_bf16(
    const float* __restrict__ src, ushort* __restrict__ dst, int n) {
  int i = (blockIdx.x * 256 + threadIdx.x) * 8;
  if (i >= n) return;
  float4 a = *(const float4*)(src + i);
  float4 b = *(const float4*)(src + i + 4);
  ushort o[8] = {f2bf(a.x), f2bf(a.y), f2bf(a.z), f2bf(a.w),
                 f2bf(b.x), f2bf(b.y), f2bf(b.z), f2bf(b.w)};
  *(uint4*)(dst + i) = *(const uint4*)o;
}

// ---------------- 64x64 tile fp32 SGEMM, C[M,N] = A[M,K] @ B[N,K]^T ----------------
__global__ __launch_bounds__(256) void sgemm64_nt(
    const float* __restrict__ A, int lda,
    const float* __restrict__ B, int ldb,
    float* __restrict__ C, int ldc, int K)
{
  __shared__ float As[16][68];
  __shared__ float Bs[16][68];
  const int tid = threadIdx.x;
  const int tx = tid & 15, ty = tid >> 4;
  const int m0 = blockIdx.y * 64, n0 = blockIdx.x * 64;
  const int f = tid & 3, r = tid >> 2;
  float acc[4][4];
#pragma unroll
  for (int i = 0; i < 4; ++i)
#pragma unroll
    for (int j = 0; j < 4; ++j) acc[i][j] = 0.f;

  for (int k0 = 0; k0 < K; k0 += 16) {
    float4 a = *(const float4*)(A + (size_t)(m0 + r) * lda + k0 + f * 4);
    float4 b = *(const float4*)(B + (size_t)(n0 + r) * ldb + k0 + f * 4);
    As[f*4+0][r] = a.x; As[f*4+1][r] = a.y; As[f*4+2][r] = a.z; As[f*4+3][r] = a.w;
    Bs[f*4+0][r] = b.x; Bs[f*4+1][r] = b.y; Bs[f*4+2][r] = b.z; Bs[f*4+3][r] = b.w;
    __syncthreads();
#pragma unroll
    for (int k = 0; k < 16; ++k) {
      float4 xa = *(const float4*)(&As[k][ty * 4]);
      float4 xb = *(const float4*)(&Bs[k][tx * 4]);
      float av[4] = {xa.x, xa.y, xa.z, xa.w};
      float bv[4] = {xb.x, xb.y, xb.z, xb.w};
#pragma unroll
      for (int i = 0; i < 4; ++i)
#pragma unroll
        for (int j = 0; j < 4; ++j) acc[i][j] = fmaf(av[i], bv[j], acc[i][j]);
    }
    __syncthreads();
  }
#pragma unroll
  for (int i = 0; i < 4; ++i) {
    float4 o = make_float4(acc[i][0], acc[i][1], acc[i][2], acc[i][3]);
    *(float4*)(C + (size_t)(m0 + ty * 4 + i) * ldc + n0 + tx * 4) = o;
  }
}

// ---------------- bf16 MFMA GEMM: C[M,N] = A[M,K] @ B[N,K]^T ----------------
// 128x128 tile, BK=32, 4 waves each computing a 64x64 quadrant as 4x4 MFMAs
// of 16x16x32. LDS row stride 40 shorts (80 B): 16B-aligned, 2-way-max banks.
// CT = ushort (bf16 out, bias ignored) or float (f32 out + bias).
template <typename CT>
__global__ __launch_bounds__(256) void gemm_bf16_nt(
    const ushort* __restrict__ A, int lda,
    const ushort* __restrict__ B, int ldb,
    CT* __restrict__ C, int ldc, int K,
    const float* __restrict__ bias)
{
  __shared__ ushort As[128 * 40];
  __shared__ ushort Bs[128 * 40];
  const int tid = threadIdx.x;
  const int m0 = blockIdx.y * 128, n0 = blockIdx.x * 128;

  const int lr = tid >> 2;        // loader row 0..63 (and +64)
  const int lc = tid & 3;         // col group of 8 bf16
  const ushort* Ap = A + (size_t)(m0 + lr) * lda + lc * 8;
  const ushort* Bp = B + (size_t)(n0 + lr) * ldb + lc * 8;

  f32x4 acc[4][4];
#pragma unroll
  for (int i = 0; i < 4; ++i)
#pragma unroll
    for (int j = 0; j < 4; ++j) acc[i][j] = (f32x4)(0.f);

  uint4 pa0 = *(const uint4*)(Ap);
  uint4 pa1 = *(const uint4*)(Ap + (size_t)64 * lda);
  uint4 pb0 = *(const uint4*)(Bp);
  uint4 pb1 = *(const uint4*)(Bp + (size_t)64 * ldb);

  const int wave = tid >> 6, lane = tid & 63;
  const int wm = (wave & 1) * 64, wn = (wave >> 1) * 64;
  const int lm = lane & 15, quad = lane >> 4;
  const ushort* Asr = As + (wm + lm) * 40 + quad * 8;
  const ushort* Bsr = Bs + (wn + lm) * 40 + quad * 8;

  for (int k0 = 32;; k0 += 32) {
    *(uint4*)(As + lr * 40 + lc * 8) = pa0;
    *(uint4*)(As + (lr + 64) * 40 + lc * 8) = pa1;
    *(uint4*)(Bs + lr * 40 + lc * 8) = pb0;
    *(uint4*)(Bs + (lr + 64) * 40 + lc * 8) = pb1;
    __syncthreads();
    const bool more = k0 < K;
    if (more) {
      pa0 = *(const uint4*)(Ap + k0);
      pa1 = *(const uint4*)(Ap + k0 + (size_t)64 * lda);
      pb0 = *(const uint4*)(Bp + k0);
      pb1 = *(const uint4*)(Bp + k0 + (size_t)64 * ldb);
    }
    short8 af[4], bfr[4];
#pragma unroll
    for (int i = 0; i < 4; ++i) {
      af[i]  = *(const short8*)(const void*)(Asr + i * 16 * 40);
      bfr[i] = *(const short8*)(const void*)(Bsr + i * 16 * 40);
    }
#pragma unroll
    for (int i = 0; i < 4; ++i)
#pragma unroll
      for (int j = 0; j < 4; ++j)
        acc[i][j] = __builtin_amdgcn_mfma_f32_16x16x32_bf16(af[i], bfr[j], acc[i][j], 0, 0, 0);
    __syncthreads();
    if (!more) break;
  }

  // epilogue: D[row = quad*4 + reg][col = lane&15] per 16x16 tile
#pragma unroll
  for (int j = 0; j < 4; ++j) {
    const int col = n0 + wn + j * 16 + lm;
    const float bb = bias ? bias[col] : 0.f;
#pragma unroll
    for (int i = 0; i < 4; ++i) {
      const int row = m0 + wm + i * 16 + quad * 4;
#pragma unroll
      for (int r = 0; r < 4; ++r) {
        const float v = acc[i][j][r] + bb;
        if constexpr (sizeof(CT) == 2)
          C[(size_t)(row + r) * ldc + col] = (CT)f2bf(v);
        else
          C[(size_t)(row + r) * ldc + col] = (CT)v;
      }
    }
  }
}

// ---------------- attention pass 1: partial (max, sumexp) per (b,h,j,chunk) ----------------
__global__ __launch_bounds__(256) void attn_pass1(
    const float* __restrict__ Q,      // [512,768] f32
    const ushort* __restrict__ KV,    // [32768,1536] bf16, K cols 0..767
    float* __restrict__ parts)        // [96][32][64][2]
{
  const int chunk = blockIdx.x, h = blockIdx.y, b = blockIdx.z;
  const int tid = threadIdx.x;
  __shared__ float Ks[128][68];
  __shared__ float rmx[64][4];
  __shared__ float rsm[64][4];
  {
    const int f = tid & 7, r0 = tid >> 3;   // f: 8-bf16 group, r0: 0..31
    const ushort* base = KV + (size_t)(b * 4096 + chunk * 128 + r0) * 1536 + h * 64 + f * 8;
#pragma unroll
    for (int rr = 0; rr < 4; ++rr) {
      uint4 raw = *(const uint4*)(base + (size_t)rr * 32 * 1536);
      const ushort* hp = (const ushort*)&raw;
      float* dst = &Ks[r0 + rr * 32][f * 8];
#pragma unroll
      for (int q = 0; q < 8; ++q) dst[q] = bf2f(hp[q]);
    }
  }
  const int j = tid >> 2, sub = tid & 3;
  float4 q[16];
  {
    const float* qrow = Q + (size_t)(b * 64 + j) * 768 + h * 64;
#pragma unroll
    for (int c = 0; c < 16; ++c) q[c] = *(const float4*)(qrow + c * 4);
  }
  __syncthreads();

  float mx = -1e30f, sm = 0.f;
  for (int i = 0; i < 32; ++i) {
    const int n = sub + i * 4;
    float s = 0.f;
#pragma unroll
    for (int c = 0; c < 16; ++c) {
      float4 k4 = *(const float4*)(&Ks[n][c * 4]);
      s = fmaf(q[c].x, k4.x, s); s = fmaf(q[c].y, k4.y, s);
      s = fmaf(q[c].z, k4.z, s); s = fmaf(q[c].w, k4.w, s);
    }
    s *= 0.125f;
    if (s > mx) { sm = sm * __expf(mx - s) + 1.f; mx = s; }
    else        { sm += __expf(s - mx); }
  }
  rmx[j][sub] = mx; rsm[j][sub] = sm;
  __syncthreads();
  if (tid < 64) {
    float m0 = rmx[tid][0], m1 = rmx[tid][1], m2 = rmx[tid][2], m3 = rmx[tid][3];
    float g = fmaxf(fmaxf(m0, m1), fmaxf(m2, m3));
    float ssum = rsm[tid][0] * __expf(m0 - g) + rsm[tid][1] * __expf(m1 - g)
               + rsm[tid][2] * __expf(m2 - g) + rsm[tid][3] * __expf(m3 - g);
    const int bh = b * 12 + h;
    float* p = parts + ((size_t)(bh * 32 + chunk) * 64 + tid) * 2;
    p[0] = g; p[1] = ssum;
  }
}

// ---------------- combine partials -> (gmax, 1/gsum) ----------------
__global__ void attn_combine(const float* __restrict__ parts, float* __restrict__ stats)
{
  const int bh = blockIdx.x, j = threadIdx.x;   // 96 blocks x 64 threads
  float pm[32], ps[32];
  float g = -1e30f;
#pragma unroll
  for (int c = 0; c < 32; ++c) {
    const float* p = parts + ((size_t)(bh * 32 + c) * 64 + j) * 2;
    pm[c] = p[0]; ps[c] = p[1];
    g = fmaxf(g, pm[c]);
  }
  float s = 0.f;
#pragma unroll
  for (int c = 0; c < 32; ++c) s += ps[c] * __expf(pm[c] - g);
  stats[(size_t)(bh * 64 + j) * 2]     = g;
  stats[(size_t)(bh * 64 + j) * 2 + 1] = 1.f / s;
}

// ---------------- pass 2: Ebf[b,n2,h*64+j] = p * V (bf16) ----------------
__global__ __launch_bounds__(256) void attn_pass2(
    const float* __restrict__ Q, const ushort* __restrict__ KV,
    const float* __restrict__ stats, ushort* __restrict__ E)
{
  const int chunk = blockIdx.x, h = blockIdx.y, b = blockIdx.z;
  const int tid = threadIdx.x;
  __shared__ float Ks[128][68];
  {
    const int f = tid & 7, r0 = tid >> 3;
    const ushort* base = KV + (size_t)(b * 4096 + chunk * 128 + r0) * 1536 + h * 64 + f * 8;
#pragma unroll
    for (int rr = 0; rr < 4; ++rr) {
      uint4 raw = *(const uint4*)(base + (size_t)rr * 32 * 1536);
      const ushort* hp = (const ushort*)&raw;
      float* dst = &Ks[r0 + rr * 32][f * 8];
#pragma unroll
      for (int q = 0; q < 8; ++q) dst[q] = bf2f(hp[q]);
    }
  }
  const int j = tid >> 2, sub = tid & 3;
  float4 q[16];
  {
    const float* qrow = Q + (size_t)(b * 64 + j) * 768 + h * 64;
#pragma unroll
    for (int c = 0; c < 16; ++c) q[c] = *(const float4*)(qrow + c * 4);
  }
  const int bh = b * 12 + h;
  const float gmax = stats[(size_t)(bh * 64 + j) * 2];
  const float ginv = stats[(size_t)(bh * 64 + j) * 2 + 1];
  __syncthreads();

  for (int i = 0; i < 32; ++i) {
    const int n = sub + i * 4;
    const int n2 = chunk * 128 + n;
    float s = 0.f;
#pragma unroll
    for (int c = 0; c < 16; ++c) {
      float4 k4 = *(const float4*)(&Ks[n][c * 4]);
      s = fmaf(q[c].x, k4.x, s); s = fmaf(q[c].y, k4.y, s);
      s = fmaf(q[c].z, k4.z, s); s = fmaf(q[c].w, k4.w, s);
    }
    s *= 0.125f;
    const float p = __expf(s - gmax) * ginv;
    const float v = bf2f(KV[(size_t)(b * 4096 + n2) * 1536 + 768 + h * 64 + j]);
    E[(size_t)(b * 4096 + n2) * 768 + h * 64 + j] = f2bf(p * v);
  }
}

extern "C" void kernel_launch(void* const* d_in, const int* in_sizes, int n_in,
                              void* d_out, int out_size, void* d_ws, size_t ws_size,
                              hipStream_t stream) {
  const float* x     = (const float*)d_in[0];   // [8,64,768]
  const float* y     = (const float*)d_in[1];   // [8,4096,768]
  const float* Wqkv  = (const float*)d_in[2];   // [2304,768]
  const float* Wproj = (const float*)d_in[3];   // [768,768]
  const float* bproj = (const float*)d_in[4];   // [768]
  float* out = (float*)d_out;                   // [8,4096,768]

  // workspace layout (bytes):
  //   Qb    f32  [512,768]      @ 0          (1,572,864)
  //   KVbf  bf16 [32768,1536]   @ 1572864    (100,663,296)
  //   ybf/Ebf bf16 [32768,768]  @ 102236160  (50,331,648)  (Ebf aliases dead ybf)
  //   wkvbf bf16 [1536,768]     @ 152567808  (2,359,296)
  //   wpbf  bf16 [768,768]      @ 154927104  (1,179,648)
  //   parts f32  [96,32,64,2]   @ 156106752  (1,572,864)
  //   stats f32  [96,64,2]      @ 157679616  (49,152)
  char* wsb = (char*)d_ws;
  float*  Qb    = (float*)(wsb + 0);
  ushort* KVbf  = (ushort*)(wsb + 1572864);
  ushort* ybf   = (ushort*)(wsb + 102236160);
  ushort* Ebf   = ybf;
  ushort* wkvbf = (ushort*)(wsb + 152567808);
  ushort* wpbf  = (ushort*)(wsb + 154927104);
  float*  parts = (float*)(wsb + 156106752);
  float*  stats = (float*)(wsb + 157679616);

  // casts to bf16
  cast_f32_bf16<<<(25165824/8 + 255)/256, 256, 0, stream>>>(y, ybf, 25165824);
  cast_f32_bf16<<<(1179648/8 + 255)/256, 256, 0, stream>>>(Wqkv + (size_t)768*768, wkvbf, 1179648);
  cast_f32_bf16<<<(589824/8 + 255)/256, 256, 0, stream>>>(Wproj, wpbf, 589824);

  // Q projection (fp32): [512,768] = x @ Wq^T
  sgemm64_nt<<<dim3(12, 8), 256, 0, stream>>>(x, 768, Wqkv, 768, Qb, 768, 768);

  // KV projection (bf16 MFMA): [32768,1536] = ybf @ wkv^T
  gemm_bf16_nt<ushort><<<dim3(12, 256), 256, 0, stream>>>(
      ybf, 768, wkvbf, 768, KVbf, 1536, 768, nullptr);

  // softmax stats (two-pass flash style)
  attn_pass1<<<dim3(32, 12, 8), 256, 0, stream>>>(Qb, KVbf, parts);
  attn_combine<<<96, 64, 0, stream>>>(parts, stats);

  // E = p * v (bf16) into Ebf
  attn_pass2<<<dim3(32, 12, 8), 256, 0, stream>>>(Qb, KVbf, stats, Ebf);

  // out = Ebf @ Wproj^T + b (bf16 MFMA, f32 out)
  gemm_bf16_nt<float><<<dim3(6, 256), 256, 0, stream>>>(
      Ebf, 768, wpbf, 768, out, 768, 768, bproj);
}

// Round 3
// 423.376 us; speedup vs baseline: 4.2728x; 1.2377x over previous
//
#include <hip/hip_runtime.h>
#include <math.h>

// B=8, N1=64, N2=4096, C=768, H=12, hd=64, scale=1/8.
// Pipeline (all big GEMMs bf16-MFMA, softmax math fp32):
//   cast x,Wqkv,Wproj,y -> bf16
//   Qbf  [512,768]    = xbf @ Wq^T        (MFMA gemm, bf16 out)
//   KVbf [32768,1536] = ybf @ Wkv^T       (MFMA gemm, bf16 out)
//   pass1 (MFMA S=QK^T) -> per-chunk (max,sumexp); combine -> (gmax, 1/gsum)
//   pass2 (MFMA S) -> Ebf[key, h*64+j] = softmax_p * V   (bf16)
//   out  [32768,768]  = Ebf @ Wproj^T + b (MFMA gemm, f32 out)

typedef __attribute__((ext_vector_type(8))) short short8;
typedef __attribute__((ext_vector_type(4))) float f32x4;

__device__ __forceinline__ ushort f2bf(float x) {
  unsigned u = __float_as_uint(x);
  u += 0x7fffu + ((u >> 16) & 1u);          // round-to-nearest-even
  return (ushort)(u >> 16);
}
__device__ __forceinline__ float bf2f(ushort h) {
  return __uint_as_float((unsigned)h << 16);
}

// async global->LDS, 16B per lane; LDS dest = wave-uniform base + lane*16
__device__ __forceinline__ void gl_lds16(const ushort* g, ushort* l) {
  __builtin_amdgcn_global_load_lds(
      (__attribute__((address_space(1))) void*)g,
      (__attribute__((address_space(3))) void*)l, 16, 0, 0);
}

// ---------------- fp32 -> bf16 cast, 8 elems/thread ----------------
__global__ __launch_bounds__(256) void cast_f32_bf16(
    const float* __restrict__ src, ushort* __restrict__ dst, int n) {
  int i = (blockIdx.x * 256 + threadIdx.x) * 8;
  if (i >= n) return;
  float4 a = *(const float4*)(src + i);
  float4 b = *(const float4*)(src + i + 4);
  ushort o[8] = {f2bf(a.x), f2bf(a.y), f2bf(a.z), f2bf(a.w),
                 f2bf(b.x), f2bf(b.y), f2bf(b.z), f2bf(b.w)};
  *(uint4*)(dst + i) = *(const uint4*)o;
}

// ---------------- bf16 MFMA GEMM: C[M,N] = A[M,K] @ B[N,K]^T ----------------
// 128x128 tile, BK=32, global_load_lds staging (double-buffered, 1 barrier/iter),
// granule swizzle sigma_r(c) = (c + (r>>1)) & 3 -> 2-way-max ds_read banks.
// XCD swizzle (swz=1): 16-row-tile bands per XCD sweeping all col tiles.
template <typename CT>
__global__ __launch_bounds__(256) void gemm_bf16_nt(
    const ushort* __restrict__ A, int lda,
    const ushort* __restrict__ B, int ldb,
    CT* __restrict__ C, int ldc, int K,
    const float* __restrict__ bias,
    int m_tiles, int n_tiles, int swz)
{
  __shared__ __align__(16) ushort As[2][4096];
  __shared__ __align__(16) ushort Bs[2][4096];
  const int tid = threadIdx.x;
  int rt, ct;
  {
    int id = blockIdx.x;
    if (swz) {
      int xcd = id & 7, local = id >> 3;
      int per = n_tiles * 16;
      int grp = local / per, s = local % per;
      rt = xcd * (m_tiles >> 3) + grp * 16 + (s & 15);
      ct = s >> 4;
    } else { rt = id % m_tiles; ct = id / m_tiles; }
  }
  const int m0 = rt * 128, n0 = ct * 128;

  const int w = tid >> 6, lane = tid & 63;
  const int lm = lane & 15, quad = lane >> 4;
  const int wm = (w & 1) * 64, wn = (w >> 1) * 64;

  // staging geometry: granule G = row*4 + p; lane covers G0 = w*64+lane, G1 = G0+256
  const int G0 = w * 64 + lane, G1 = G0 + 256;
  const int r0 = G0 >> 2, c0 = ((G0 & 3) - (r0 >> 1)) & 3;
  const int r1 = G1 >> 2, c1 = ((G1 & 3) - (r1 >> 1)) & 3;
  const ushort* Ag0 = A + (size_t)(m0 + r0) * lda + c0 * 8;
  const ushort* Ag1 = A + (size_t)(m0 + r1) * lda + c1 * 8;
  const ushort* Bg0 = B + (size_t)(n0 + r0) * ldb + c0 * 8;
  const ushort* Bg1 = B + (size_t)(n0 + r1) * ldb + c1 * 8;
  const int lds0 = w * 512, lds1 = w * 512 + 2048;   // ushort offsets

  f32x4 acc[4][4];
#pragma unroll
  for (int i = 0; i < 4; ++i)
#pragma unroll
    for (int j = 0; j < 4; ++j) acc[i][j] = (f32x4)(0.f);

  const int nk = K >> 5;
  // prologue loads -> buf0
  gl_lds16(Ag0, &As[0][lds0]); gl_lds16(Ag1, &As[0][lds1]);
  gl_lds16(Bg0, &Bs[0][lds0]); gl_lds16(Bg1, &Bs[0][lds1]);

  int cur = 0;
  for (int kk = 0; kk < nk; ++kk) {
    __syncthreads();   // drains vmcnt: buf[cur] ready; prev reads of buf[cur^1] done
    if (kk + 1 < nk) {
      const int k0 = (kk + 1) << 5;
      gl_lds16(Ag0 + k0, &As[cur ^ 1][lds0]); gl_lds16(Ag1 + k0, &As[cur ^ 1][lds1]);
      gl_lds16(Bg0 + k0, &Bs[cur ^ 1][lds0]); gl_lds16(Bg1 + k0, &Bs[cur ^ 1][lds1]);
    }
    const ushort* Ab = &As[cur][0];
    const ushort* Bb = &Bs[cur][0];
    short8 af[4], bf8[4];
#pragma unroll
    for (int i = 0; i < 4; ++i) {
      const int Ra = wm + i * 16 + lm;
      af[i] = *(const short8*)(const void*)(Ab + Ra * 32 + ((quad + (Ra >> 1)) & 3) * 8);
      const int Rb = wn + i * 16 + lm;
      bf8[i] = *(const short8*)(const void*)(Bb + Rb * 32 + ((quad + (Rb >> 1)) & 3) * 8);
    }
#pragma unroll
    for (int i = 0; i < 4; ++i)
#pragma unroll
      for (int j = 0; j < 4; ++j)
        acc[i][j] = __builtin_amdgcn_mfma_f32_16x16x32_bf16(af[i], bf8[j], acc[i][j], 0, 0, 0);
    cur ^= 1;
  }
  __syncthreads();   // LDS free for epilogue scratch

  if constexpr (sizeof(CT) == 2) {
    // bf16 out: LDS-bounce to coalesced dwordx4 stores. 4KB scratch/wave in Bs.
    ushort* eb = ((ushort*)&Bs[0][0]) + w * 2048;
#pragma unroll
    for (int i = 0; i < 4; ++i) {
      ushort* ebc = eb + (i & 1) * 1024;    // ping-pong between chunks
#pragma unroll
      for (int j = 0; j < 4; ++j)
#pragma unroll
        for (int r = 0; r < 4; ++r) {
          const int R = quad * 4 + r;
          const int gt = j * 2 + (lm >> 3);
          const int gs = (gt + R) & 7;      // granule swizzle
          ebc[R * 64 + gs * 8 + (lm & 7)] = f2bf(acc[i][j][r]);
        }
#pragma unroll
      for (int p = 0; p < 2; ++p) {
        const int R2 = (lane >> 3) + p * 8;
        const int g = lane & 7;
        const int gt2 = (g - R2) & 7;
        uint4 v = *(const uint4*)(const void*)(ebc + R2 * 64 + g * 8);
        *(uint4*)(C + (size_t)(m0 + wm + i * 16 + R2) * ldc + n0 + wn + gt2 * 8) = v;
      }
    }
  } else {
    // f32 out + bias
#pragma unroll
    for (int j = 0; j < 4; ++j) {
      const int col = n0 + wn + j * 16 + lm;
      const float bb = bias ? bias[col] : 0.f;
#pragma unroll
      for (int i = 0; i < 4; ++i) {
        const int row = m0 + wm + i * 16 + quad * 4;
#pragma unroll
        for (int r = 0; r < 4; ++r)
          C[(size_t)(row + r) * ldc + col] = (CT)(acc[i][j][r] + bb);
      }
    }
  }
}

// ---------------- pass 1: MFMA S=QK^T, per-chunk (max,sumexp) ----------------
// grid (32 chunks, 12 h, 8 b), 256 threads. Wave w: keys [w*32, w*32+32).
__global__ __launch_bounds__(256) void attn_pass1(
    const ushort* __restrict__ Q,     // [512,768] bf16
    const ushort* __restrict__ KV,    // [32768,1536] bf16, K cols 0..767
    float* __restrict__ parts)        // [96][32][64][2]
{
  const int chunk = blockIdx.x, h = blockIdx.y, b = blockIdx.z;
  const int tid = threadIdx.x;
  __shared__ __align__(16) ushort Qs[64 * 72];
  __shared__ __align__(16) ushort Ks[128 * 72];
  __shared__ float sm[4][64], ss[4][64];
#pragma unroll
  for (int p = 0; p < 2; ++p) {
    const int G = tid + 256 * p, row = G >> 3, g = G & 7;
    *(uint4*)(Qs + row * 72 + g * 8) =
        *(const uint4*)(Q + (size_t)(b * 64 + row) * 768 + h * 64 + g * 8);
  }
#pragma unroll
  for (int p = 0; p < 4; ++p) {
    const int G = tid + 256 * p, row = G >> 3, g = G & 7;
    *(uint4*)(Ks + row * 72 + g * 8) =
        *(const uint4*)(KV + (size_t)(b * 4096 + chunk * 128 + row) * 1536 + h * 64 + g * 8);
  }
  __syncthreads();

  const int w = tid >> 6, lane = tid & 63;
  const int lm = lane & 15, quad = lane >> 4;
  const int wn = w * 32;

  f32x4 acc[4][2];
#pragma unroll
  for (int i = 0; i < 4; ++i) { acc[i][0] = (f32x4)(0.f); acc[i][1] = (f32x4)(0.f); }
#pragma unroll
  for (int s = 0; s < 2; ++s) {
    short8 qf[4], kf[2];
#pragma unroll
    for (int i = 0; i < 4; ++i)
      qf[i] = *(const short8*)(const void*)(Qs + (i * 16 + lm) * 72 + s * 32 + quad * 8);
#pragma unroll
    for (int jn = 0; jn < 2; ++jn)
      kf[jn] = *(const short8*)(const void*)(Ks + (wn + jn * 16 + lm) * 72 + s * 32 + quad * 8);
#pragma unroll
    for (int i = 0; i < 4; ++i)
#pragma unroll
      for (int jn = 0; jn < 2; ++jn)
        acc[i][jn] = __builtin_amdgcn_mfma_f32_16x16x32_bf16(qf[i], kf[jn], acc[i][jn], 0, 0, 0);
  }

#pragma unroll
  for (int i = 0; i < 4; ++i)
#pragma unroll
    for (int r = 0; r < 4; ++r) {
      float v0 = acc[i][0][r] * 0.125f, v1 = acc[i][1][r] * 0.125f;
      float m = fmaxf(v0, v1);
      m = fmaxf(m, __shfl_xor(m, 1)); m = fmaxf(m, __shfl_xor(m, 2));
      m = fmaxf(m, __shfl_xor(m, 4)); m = fmaxf(m, __shfl_xor(m, 8));
      float e = __expf(v0 - m) + __expf(v1 - m);
      e += __shfl_xor(e, 1); e += __shfl_xor(e, 2);
      e += __shfl_xor(e, 4); e += __shfl_xor(e, 8);
      if (lm == 0) {
        const int j = i * 16 + quad * 4 + r;
        sm[w][j] = m; ss[w][j] = e;
      }
    }
  __syncthreads();
  if (tid < 64) {
    float g = fmaxf(fmaxf(sm[0][tid], sm[1][tid]), fmaxf(sm[2][tid], sm[3][tid]));
    float s = ss[0][tid] * __expf(sm[0][tid] - g) + ss[1][tid] * __expf(sm[1][tid] - g)
            + ss[2][tid] * __expf(sm[2][tid] - g) + ss[3][tid] * __expf(sm[3][tid] - g);
    const int bh = b * 12 + h;
    float* p = parts + ((size_t)(bh * 32 + chunk) * 64 + tid) * 2;
    p[0] = g; p[1] = s;
  }
}

// ---------------- combine partials -> (gmax, 1/gsum) ----------------
__global__ void attn_combine(const float* __restrict__ parts, float* __restrict__ stats)
{
  const int bh = blockIdx.x, j = threadIdx.x;   // 96 blocks x 64 threads
  float pm[32], ps[32];
  float g = -1e30f;
#pragma unroll
  for (int c = 0; c < 32; ++c) {
    const float* p = parts + ((size_t)(bh * 32 + c) * 64 + j) * 2;
    pm[c] = p[0]; ps[c] = p[1];
    g = fmaxf(g, pm[c]);
  }
  float s = 0.f;
#pragma unroll
  for (int c = 0; c < 32; ++c) s += ps[c] * __expf(pm[c] - g);
  stats[(size_t)(bh * 64 + j) * 2]     = g;
  stats[(size_t)(bh * 64 + j) * 2 + 1] = 1.f / s;
}

// ---------------- pass 2: MFMA S, Ebf[key, h*64+j] = p * V ----------------
__global__ __launch_bounds__(256) void attn_pass2(
    const ushort* __restrict__ Q, const ushort* __restrict__ KV,
    const float* __restrict__ stats, ushort* __restrict__ E)
{
  const int chunk = blockIdx.x, h = blockIdx.y, b = blockIdx.z;
  const int tid = threadIdx.x;
  __shared__ __align__(16) ushort Qs[64 * 72];
  __shared__ __align__(16) ushort Ks[128 * 72];
  __shared__ __align__(16) ushort Vs[128 * 72];
  __shared__ float st[64][2];
#pragma unroll
  for (int p = 0; p < 2; ++p) {
    const int G = tid + 256 * p, row = G >> 3, g = G & 7;
    *(uint4*)(Qs + row * 72 + g * 8) =
        *(const uint4*)(Q + (size_t)(b * 64 + row) * 768 + h * 64 + g * 8);
  }
#pragma unroll
  for (int p = 0; p < 4; ++p) {
    const int G = tid + 256 * p, row = G >> 3, g = G & 7;
    const size_t rbase = (size_t)(b * 4096 + chunk * 128 + row) * 1536 + h * 64 + g * 8;
    *(uint4*)(Ks + row * 72 + g * 8) = *(const uint4*)(KV + rbase);
    *(uint4*)(Vs + row * 72 + g * 8) = *(const uint4*)(KV + rbase + 768);
  }
  const int bh = b * 12 + h;
  if (tid < 128) st[tid >> 1][tid & 1] = stats[(size_t)(bh * 64 + (tid >> 1)) * 2 + (tid & 1)];
  __syncthreads();

  const int w = tid >> 6, lane = tid & 63;
  const int lm = lane & 15, quad = lane >> 4;
  const int wn = w * 32;

  f32x4 acc[4][2];
#pragma unroll
  for (int i = 0; i < 4; ++i) { acc[i][0] = (f32x4)(0.f); acc[i][1] = (f32x4)(0.f); }
#pragma unroll
  for (int s = 0; s < 2; ++s) {
    short8 qf[4], kf[2];
#pragma unroll
    for (int i = 0; i < 4; ++i)
      qf[i] = *(const short8*)(const void*)(Qs + (i * 16 + lm) * 72 + s * 32 + quad * 8);
#pragma unroll
    for (int jn = 0; jn < 2; ++jn)
      kf[jn] = *(const short8*)(const void*)(Ks + (wn + jn * 16 + lm) * 72 + s * 32 + quad * 8);
#pragma unroll
    for (int i = 0; i < 4; ++i)
#pragma unroll
      for (int jn = 0; jn < 2; ++jn)
        acc[i][jn] = __builtin_amdgcn_mfma_f32_16x16x32_bf16(qf[i], kf[jn], acc[i][jn], 0, 0, 0);
  }

  ushort ev[4][2][4];
#pragma unroll
  for (int i = 0; i < 4; ++i)
#pragma unroll
    for (int jn = 0; jn < 2; ++jn)
#pragma unroll
      for (int r = 0; r < 4; ++r) {
        const float v = acc[i][jn][r] * 0.125f;
        const int j = i * 16 + quad * 4 + r;
        const float p = __expf(v - st[j][0]) * st[j][1];
        const int key = wn + jn * 16 + lm;
        ev[i][jn][r] = f2bf(p * bf2f(Vs[key * 72 + j]));
      }
  __syncthreads();                 // all frag reads of Ks done -> reuse as E staging
  ushort* Es = Ks;
#pragma unroll
  for (int i = 0; i < 4; ++i)
#pragma unroll
    for (int jn = 0; jn < 2; ++jn)
#pragma unroll
      for (int r = 0; r < 4; ++r)
        Es[(wn + jn * 16 + lm) * 72 + i * 16 + quad * 4 + r] = ev[i][jn][r];
  __syncthreads();
#pragma unroll
  for (int k = 0; k < 4; ++k) {
    const int row = tid >> 1, g = (tid & 1) * 4 + k;
    uint4 v = *(const uint4*)(const void*)(Es + row * 72 + g * 8);
    *(uint4*)(E + (size_t)(b * 4096 + chunk * 128 + row) * 768 + h * 64 + g * 8) = v;
  }
}

extern "C" void kernel_launch(void* const* d_in, const int* in_sizes, int n_in,
                              void* d_out, int out_size, void* d_ws, size_t ws_size,
                              hipStream_t stream) {
  const float* x     = (const float*)d_in[0];   // [8,64,768]
  const float* y     = (const float*)d_in[1];   // [8,4096,768]
  const float* Wqkv  = (const float*)d_in[2];   // [2304,768]
  const float* Wproj = (const float*)d_in[3];   // [768,768]
  const float* bproj = (const float*)d_in[4];   // [768]
  float* out = (float*)d_out;                   // [8,4096,768]

  // workspace layout (bytes), total 157,286,400 (< proven 157.7 MB):
  //   xbf    bf16 [512,768]    @ 0
  //   qbf    bf16 [512,768]    @ 786432
  //   wqkvbf bf16 [2304,768]   @ 1572864   (3,538,944) -- dead after KV gemm
  //     parts f32 [96,32,64,2] @ 1572864   (alias, used after)
  //     stats f32 [96,64,2]    @ 3145728   (alias)
  //   wpbf   bf16 [768,768]    @ 5111808
  //   ybf/Ebf bf16 [32768,768] @ 6291456   (Ebf aliases dead ybf)
  //   KVbf   bf16 [32768,1536] @ 56623104
  char* wsb = (char*)d_ws;
  ushort* xbf    = (ushort*)(wsb + 0);
  ushort* qbf    = (ushort*)(wsb + 786432);
  ushort* wqkvbf = (ushort*)(wsb + 1572864);
  float*  parts  = (float*)(wsb + 1572864);
  float*  stats  = (float*)(wsb + 3145728);
  ushort* wpbf   = (ushort*)(wsb + 5111808);
  ushort* ybf    = (ushort*)(wsb + 6291456);
  ushort* Ebf    = ybf;
  ushort* KVbf   = (ushort*)(wsb + 56623104);

  // casts
  cast_f32_bf16<<<(393216/8 + 255)/256, 256, 0, stream>>>(x, xbf, 393216);
  cast_f32_bf16<<<(1769472/8 + 255)/256, 256, 0, stream>>>(Wqkv, wqkvbf, 1769472);
  cast_f32_bf16<<<(589824/8 + 255)/256, 256, 0, stream>>>(Wproj, wpbf, 589824);
  cast_f32_bf16<<<(25165824/8 + 255)/256, 256, 0, stream>>>(y, ybf, 25165824);

  // Q projection: [512,768] = xbf @ Wq^T (bf16 out)
  gemm_bf16_nt<ushort><<<24, 256, 0, stream>>>(
      xbf, 768, wqkvbf, 768, qbf, 768, 768, nullptr, 4, 6, 0);
  // KV projection: [32768,1536] = ybf @ Wkv^T (bf16 out)
  gemm_bf16_nt<ushort><<<3072, 256, 0, stream>>>(
      ybf, 768, wqkvbf + (size_t)768 * 768, 768, KVbf, 1536, 768, nullptr, 256, 12, 1);

  // softmax stats (two-pass flash style, MFMA S)
  attn_pass1<<<dim3(32, 12, 8), 256, 0, stream>>>(qbf, KVbf, parts);
  attn_combine<<<96, 64, 0, stream>>>(parts, stats);
  attn_pass2<<<dim3(32, 12, 8), 256, 0, stream>>>(qbf, KVbf, stats, Ebf);

  // out = Ebf @ Wproj^T + b (f32 out)
  gemm_bf16_nt<float><<<1536, 256, 0, stream>>>(
      Ebf, 768, wpbf, 768, out, 768, 768, bproj, 256, 6, 1);
}